// Round 2
// baseline (726.781 us; speedup 1.0000x reference)
//
#include <hip/hip_runtime.h>

#define NUM_NODES 50000
#define DIM 64

// One edge is handled by 16 consecutive threads; each thread owns a float4
// chunk (4 features). Gather x[row[e]] (contiguous 256B per edge -> coalesced
// within the 16-thread group), scatter-add into out[col[e]] via f32 atomics.
__global__ void scatter_add_kernel(const float* __restrict__ x,
                                   const int* __restrict__ row,
                                   const int* __restrict__ col,
                                   float* __restrict__ out,
                                   int* __restrict__ cnt,
                                   int num_edges) {
    int t = blockIdx.x * blockDim.x + threadIdx.x;
    int total = num_edges * 16;
    if (t >= total) return;
    int e = t >> 4;      // edge id
    int c = t & 15;      // float4 chunk id within the 64-dim feature
    int src = row[e];    // 16 threads read same addr -> wave broadcast
    int dst = col[e];
    const float4 v = *reinterpret_cast<const float4*>(x + (size_t)src * DIM + c * 4);
    float* o = out + (size_t)dst * DIM + c * 4;
    atomicAdd(o + 0, v.x);
    atomicAdd(o + 1, v.y);
    atomicAdd(o + 2, v.z);
    atomicAdd(o + 3, v.w);
    if (c == 0) atomicAdd(cnt + dst, 1);
}

// out[n][d] /= max(cnt[n], 1)  -- vectorized as float4 per thread.
__global__ void divide_kernel(float* __restrict__ out,
                              const int* __restrict__ cnt,
                              int num_nodes) {
    int t = blockIdx.x * blockDim.x + threadIdx.x;
    if (t >= num_nodes * 16) return;
    int node = t >> 4;
    int c = t & 15;
    float inv = 1.0f / fmaxf((float)cnt[node], 1.0f);
    float4* p = reinterpret_cast<float4*>(out + (size_t)node * DIM + c * 4);
    float4 v = *p;
    v.x *= inv; v.y *= inv; v.z *= inv; v.w *= inv;
    *p = v;
}

extern "C" void kernel_launch(void* const* d_in, const int* in_sizes, int n_in,
                              void* d_out, int out_size, void* d_ws, size_t ws_size,
                              hipStream_t stream) {
    const float* x = (const float*)d_in[0];
    const int* edge_index = (const int*)d_in[1];  // [2, E] flat: row then col
    int num_edges = in_sizes[1] / 2;
    const int* row = edge_index;
    const int* col = edge_index + num_edges;

    float* out = (float*)d_out;
    int* cnt = (int*)d_ws;  // NUM_NODES ints

    // Harness poisons d_out/d_ws to 0xAA once; zero them ourselves every call.
    hipMemsetAsync(out, 0, (size_t)out_size * sizeof(float), stream);
    hipMemsetAsync(cnt, 0, (size_t)NUM_NODES * sizeof(int), stream);

    {
        int total = num_edges * 16;
        int block = 256;
        int grid = (total + block - 1) / block;
        scatter_add_kernel<<<grid, block, 0, stream>>>(x, row, col, out, cnt, num_edges);
    }
    {
        int total = NUM_NODES * 16;
        int block = 256;
        int grid = (total + block - 1) / block;
        divide_kernel<<<grid, block, 0, stream>>>(out, cnt, NUM_NODES);
    }
}

// Round 3
// 234.400 us; speedup vs baseline: 3.1006x; 3.1006x over previous
//
#include <hip/hip_runtime.h>

#define NUM_NODES 50000
#define DIM 64
#define SCAN_BLOCK 1024

// -------- pass 1: histogram of destination nodes --------
__global__ void hist_kernel(const int* __restrict__ col, int* __restrict__ cnt, int E) {
    int e = blockIdx.x * blockDim.x + threadIdx.x;
    if (e < E) atomicAdd(&cnt[col[e]], 1);
}

// -------- pass 2: single-block exclusive scan over cnt -> offsets, pos --------
__global__ void scan_kernel(const int* __restrict__ cnt, int* __restrict__ offsets,
                            int* __restrict__ pos, int n) {
    __shared__ int sm[SCAN_BLOCK];
    __shared__ int carry_sm;
    int tid = threadIdx.x;
    if (tid == 0) carry_sm = 0;
    __syncthreads();
    for (int base = 0; base < n; base += SCAN_BLOCK) {
        int i = base + tid;
        int v = (i < n) ? cnt[i] : 0;
        sm[tid] = v;
        __syncthreads();
        // Hillis-Steele inclusive scan in LDS
        for (int ofs = 1; ofs < SCAN_BLOCK; ofs <<= 1) {
            int t = (tid >= ofs) ? sm[tid - ofs] : 0;
            __syncthreads();
            sm[tid] += t;
            __syncthreads();
        }
        int incl = sm[tid];
        int excl = incl - v;
        int carry = carry_sm;
        if (i < n) {
            offsets[i] = carry + excl;
            pos[i]     = carry + excl;
        }
        __syncthreads();
        if (tid == SCAN_BLOCK - 1) carry_sm = carry + incl;
        __syncthreads();
    }
}

// -------- pass 3: counting-sort scatter of source ids by destination --------
__global__ void scatter_kernel(const int* __restrict__ row, const int* __restrict__ col,
                               int* __restrict__ pos, int* __restrict__ sorted_src, int E) {
    int e = blockIdx.x * blockDim.x + threadIdx.x;
    if (e < E) {
        int p = atomicAdd(&pos[col[e]], 1);
        sorted_src[p] = row[e];
    }
}

// -------- pass 4: per-node owner reduction + mean (no atomics) --------
// One wave (64 threads) per node; lane owns one feature dim.
__global__ void aggregate_kernel(const float* __restrict__ x,
                                 const int* __restrict__ sorted_src,
                                 const int* __restrict__ offsets,
                                 const int* __restrict__ cnt,
                                 float* __restrict__ out) {
    int n = blockIdx.x;
    int lane = threadIdx.x;  // 0..63
    int start = offsets[n];
    int deg = cnt[n];
    float acc = 0.0f;
    for (int i = 0; i < deg; i += 64) {
        // cooperatively load up to 64 edge source ids, broadcast via shfl
        int mysrc = (i + lane < deg) ? sorted_src[start + i + lane] : 0;
        int m = min(64, deg - i);
        for (int j = 0; j < m; ++j) {
            int s = __shfl(mysrc, j);
            acc += x[(size_t)s * DIM + lane];  // coalesced 256B row read
        }
    }
    float inv = (deg > 0) ? (1.0f / (float)deg) : 0.0f;
    out[(size_t)n * DIM + lane] = acc * inv;
}

extern "C" void kernel_launch(void* const* d_in, const int* in_sizes, int n_in,
                              void* d_out, int out_size, void* d_ws, size_t ws_size,
                              hipStream_t stream) {
    const float* x = (const float*)d_in[0];
    const int* edge_index = (const int*)d_in[1];  // [2, E] flat: row then col
    int E = in_sizes[1] / 2;
    const int* row = edge_index;
    const int* col = edge_index + E;
    float* out = (float*)d_out;

    // workspace layout
    int* cnt        = (int*)d_ws;                 // NUM_NODES
    int* offsets    = cnt + NUM_NODES;            // NUM_NODES
    int* pos        = offsets + NUM_NODES;        // NUM_NODES
    int* sorted_src = pos + NUM_NODES;            // E

    hipMemsetAsync(cnt, 0, (size_t)NUM_NODES * sizeof(int), stream);

    {
        int block = 256, grid = (E + block - 1) / block;
        hist_kernel<<<grid, block, 0, stream>>>(col, cnt, E);
    }
    scan_kernel<<<1, SCAN_BLOCK, 0, stream>>>(cnt, offsets, pos, NUM_NODES);
    {
        int block = 256, grid = (E + block - 1) / block;
        scatter_kernel<<<grid, block, 0, stream>>>(row, col, pos, sorted_src, E);
    }
    aggregate_kernel<<<NUM_NODES, 64, 0, stream>>>(x, sorted_src, offsets, cnt, out);
}

// Round 4
// 151.768 us; speedup vs baseline: 4.7887x; 1.5445x over previous
//
#include <hip/hip_runtime.h>

#define NUM_NODES 50000
#define DIM 64

// -------- pass 1: histogram of destination nodes --------
__global__ void hist_kernel(const int* __restrict__ col, int* __restrict__ cnt, int E) {
    int e = blockIdx.x * blockDim.x + threadIdx.x;
    if (e < E) atomicAdd(&cnt[col[e]], 1);
}

// -------- pass 2a: per-block scan (1024 elems/block, int4 per thread) --------
// Writes per-block exclusive scan into offsets[], per-block total into blocksums[].
__global__ void scan_blocks_kernel(const int* __restrict__ cnt,
                                   int* __restrict__ offsets,
                                   int* __restrict__ blocksums, int n) {
    int tid = threadIdx.x;                       // 0..255
    int base = blockIdx.x * 1024 + tid * 4;
    int4 v = make_int4(0, 0, 0, 0);
    if (base + 3 < n) {
        v = *reinterpret_cast<const int4*>(cnt + base);
    } else {
        if (base + 0 < n) v.x = cnt[base + 0];
        if (base + 1 < n) v.y = cnt[base + 1];
        if (base + 2 < n) v.z = cnt[base + 2];
        if (base + 3 < n) v.w = cnt[base + 3];
    }
    int local = v.x + v.y + v.z + v.w;
    int lane = tid & 63;
    int wid = tid >> 6;
    int incl = local;
    #pragma unroll
    for (int ofs = 1; ofs < 64; ofs <<= 1) {
        int t = __shfl_up(incl, ofs);
        if (lane >= ofs) incl += t;
    }
    __shared__ int wsum[4];
    if (lane == 63) wsum[wid] = incl;
    __syncthreads();
    int wprefix = 0;
    for (int w = 0; w < wid; ++w) wprefix += wsum[w];
    int excl = wprefix + incl - local;           // exclusive prefix of this thread's 4-group
    int o0 = excl;
    int o1 = o0 + v.x;
    int o2 = o1 + v.y;
    int o3 = o2 + v.z;
    if (base + 3 < n) {
        *reinterpret_cast<int4*>(offsets + base) = make_int4(o0, o1, o2, o3);
    } else {
        if (base + 0 < n) offsets[base + 0] = o0;
        if (base + 1 < n) offsets[base + 1] = o1;
        if (base + 2 < n) offsets[base + 2] = o2;
        if (base + 3 < n) offsets[base + 3] = o3;
    }
    if (tid == 255) blocksums[blockIdx.x] = wprefix + incl;   // block total
}

// -------- pass 2b: exclusive scan of block sums (single wave, carry loop) ----
__global__ void scan_sums_kernel(int* __restrict__ blocksums, int nb) {
    int lane = threadIdx.x;  // 0..63
    int carry = 0;
    for (int b = 0; b < nb; b += 64) {
        int i = b + lane;
        int v = (i < nb) ? blocksums[i] : 0;
        int incl = v;
        #pragma unroll
        for (int ofs = 1; ofs < 64; ofs <<= 1) {
            int t = __shfl_up(incl, ofs);
            if (lane >= ofs) incl += t;
        }
        if (i < nb) blocksums[i] = carry + incl - v;   // exclusive
        int tot = __shfl(incl, 63);
        carry += tot;
    }
}

// -------- pass 2c: add block offsets, fan out to offsets[] and pos[] --------
__global__ void scan_add_kernel(const int* __restrict__ blocksums,
                                int* __restrict__ offsets,
                                int* __restrict__ pos, int n) {
    int base = blockIdx.x * 1024 + threadIdx.x * 4;
    int add = blocksums[blockIdx.x];
    if (base + 3 < n) {
        int4 s = *reinterpret_cast<const int4*>(offsets + base);
        s.x += add; s.y += add; s.z += add; s.w += add;
        *reinterpret_cast<int4*>(offsets + base) = s;
        *reinterpret_cast<int4*>(pos + base) = s;
    } else {
        for (int k = 0; k < 4; ++k)
            if (base + k < n) {
                int s = offsets[base + k] + add;
                offsets[base + k] = s;
                pos[base + k] = s;
            }
    }
}

// -------- pass 3: counting-sort scatter of source ids by destination --------
__global__ void scatter_kernel(const int* __restrict__ row, const int* __restrict__ col,
                               int* __restrict__ pos, int* __restrict__ sorted_src, int E) {
    int e = blockIdx.x * blockDim.x + threadIdx.x;
    if (e < E) {
        int p = atomicAdd(&pos[col[e]], 1);
        sorted_src[p] = row[e];
    }
}

// -------- pass 4: per-node owner reduction + mean (no atomics) --------
// One wave (64 threads) per node; lane owns one feature dim.
__global__ void aggregate_kernel(const float* __restrict__ x,
                                 const int* __restrict__ sorted_src,
                                 const int* __restrict__ offsets,
                                 const int* __restrict__ cnt,
                                 float* __restrict__ out) {
    int n = blockIdx.x;
    int lane = threadIdx.x;  // 0..63
    int start = offsets[n];
    int deg = cnt[n];
    float acc = 0.0f;
    for (int i = 0; i < deg; i += 64) {
        int mysrc = (i + lane < deg) ? sorted_src[start + i + lane] : 0;
        int m = min(64, deg - i);
        for (int j = 0; j < m; ++j) {
            int s = __shfl(mysrc, j);
            acc += x[(size_t)s * DIM + lane];  // coalesced 256B row read
        }
    }
    float inv = (deg > 0) ? (1.0f / (float)deg) : 0.0f;
    out[(size_t)n * DIM + lane] = acc * inv;
}

extern "C" void kernel_launch(void* const* d_in, const int* in_sizes, int n_in,
                              void* d_out, int out_size, void* d_ws, size_t ws_size,
                              hipStream_t stream) {
    const float* x = (const float*)d_in[0];
    const int* edge_index = (const int*)d_in[1];  // [2, E] flat: row then col
    int E = in_sizes[1] / 2;
    const int* row = edge_index;
    const int* col = edge_index + E;
    float* out = (float*)d_out;

    int nblk = (NUM_NODES + 1023) / 1024;         // 49

    // workspace layout
    int* cnt        = (int*)d_ws;                 // NUM_NODES
    int* offsets    = cnt + NUM_NODES;            // NUM_NODES
    int* pos        = offsets + NUM_NODES;        // NUM_NODES
    int* blocksums  = pos + NUM_NODES;            // nblk (pad 64)
    int* sorted_src = blocksums + 64;             // E

    hipMemsetAsync(cnt, 0, (size_t)NUM_NODES * sizeof(int), stream);

    {
        int block = 256, grid = (E + block - 1) / block;
        hist_kernel<<<grid, block, 0, stream>>>(col, cnt, E);
    }
    scan_blocks_kernel<<<nblk, 256, 0, stream>>>(cnt, offsets, blocksums, NUM_NODES);
    scan_sums_kernel<<<1, 64, 0, stream>>>(blocksums, nblk);
    scan_add_kernel<<<nblk, 256, 0, stream>>>(blocksums, offsets, pos, NUM_NODES);
    {
        int block = 256, grid = (E + block - 1) / block;
        scatter_kernel<<<grid, block, 0, stream>>>(row, col, pos, sorted_src, E);
    }
    aggregate_kernel<<<NUM_NODES, 64, 0, stream>>>(x, sorted_src, offsets, cnt, out);
}

// Round 5
// 87.415 us; speedup vs baseline: 8.3142x; 1.7362x over previous
//
#include <hip/hip_runtime.h>

#define N_NODES 50000
#define DIM 64
#define NPB 64                                  // nodes per bucket (dst >> 6)
#define NB ((N_NODES + NPB - 1) / NPB)          // 782 buckets
#define NCHUNK 128                              // edge chunks (= binning blocks)
#define CAP 2048                                // B4 per-chunk LDS capacity (edges)

// ---- B3a: per-chunk bucket histogram (LDS-privatized) + bucket totals ----
__global__ void bucket_hist_kernel(const int* __restrict__ col,
                                   int* __restrict__ localH,
                                   int* __restrict__ bucket_total,
                                   int E, int chunk) {
    __shared__ int h[NB];
    int c = blockIdx.x;
    for (int b = threadIdx.x; b < NB; b += blockDim.x) h[b] = 0;
    __syncthreads();
    int beg = c * chunk, end = min(beg + chunk, E);
    for (int e = beg + threadIdx.x; e < end; e += blockDim.x)
        atomicAdd(&h[col[e] >> 6], 1);
    __syncthreads();
    for (int b = threadIdx.x; b < NB; b += blockDim.x) {
        int v = h[b];
        localH[c * NB + b] = v;                 // coalesced per-block row write
        if (v) atomicAdd(&bucket_total[b], v);
    }
}

// ---- B3b0: exclusive scan of bucket totals -> bucket_base[0..NB] ----
__global__ void bucket_scan_kernel(const int* __restrict__ bucket_total,
                                   int* __restrict__ bucket_base) {
    int lane = threadIdx.x;                     // single wave
    int carry = 0;
    for (int b0 = 0; b0 < NB; b0 += 64) {
        int i = b0 + lane;
        int v = (i < NB) ? bucket_total[i] : 0;
        int incl = v;
        #pragma unroll
        for (int ofs = 1; ofs < 64; ofs <<= 1) {
            int t = __shfl_up(incl, ofs);
            if (lane >= ofs) incl += t;
        }
        if (i < NB) bucket_base[i] = carry + incl - v;
        carry += __shfl(incl, 63);
    }
    if (lane == 0) bucket_base[NB] = carry;
}

// ---- B3b: per-bucket prefix over chunks; IN-PLACE: localH becomes startpos ----
__global__ void chunk_offset_kernel(int* __restrict__ localH,
                                    const int* __restrict__ bucket_base) {
    int b = blockIdx.x;
    int lane = threadIdx.x;                     // single wave per bucket
    int running = bucket_base[b];
    for (int c0 = 0; c0 < NCHUNK; c0 += 64) {
        int c = c0 + lane;
        int v = (c < NCHUNK) ? localH[c * NB + b] : 0;
        int incl = v;
        #pragma unroll
        for (int ofs = 1; ofs < 64; ofs <<= 1) {
            int t = __shfl_up(incl, ofs);
            if (lane >= ofs) incl += t;
        }
        if (c < NCHUNK) localH[c * NB + b] = running + incl - v;
        running += __shfl(incl, 63);
    }
}

// ---- B3c: binning scatter — NO global atomics; block-exclusive regions ----
__global__ void binning_kernel(const int* __restrict__ row,
                               const int* __restrict__ col,
                               const int* __restrict__ startpos,
                               unsigned int* __restrict__ packed,
                               int E, int chunk) {
    __shared__ int cursor[NB];
    int c = blockIdx.x;
    for (int b = threadIdx.x; b < NB; b += blockDim.x)
        cursor[b] = startpos[c * NB + b];
    __syncthreads();
    int beg = c * chunk, end = min(beg + chunk, E);
    for (int e = beg + threadIdx.x; e < end; e += blockDim.x) {
        int d = col[e];
        int s = row[e];
        int p = atomicAdd(&cursor[d >> 6], 1);  // LDS atomic only
        packed[p] = (unsigned)s | ((unsigned)(d & 63) << 16);
    }
}

// ---- B4: fused per-bucket counting sort (in LDS) + aggregate + mean ----
__global__ void aggregate_bucket_kernel(const float* __restrict__ x,
                                        const unsigned int* __restrict__ packed,
                                        const int* __restrict__ bucket_base,
                                        float* __restrict__ out) {
    __shared__ unsigned int buf[CAP];
    __shared__ unsigned short srcs[CAP];
    __shared__ int hist[NPB];
    __shared__ int segoff[NPB];
    __shared__ int cursor[NPB];
    __shared__ int cnt_tot[NPB];

    int b = blockIdx.x;
    int tid = threadIdx.x;
    int lane = tid & 63;
    int wid = tid >> 6;                         // 0..3
    int seg_beg = bucket_base[b];
    int seg_end = bucket_base[b + 1];
    int node_base = b * NPB;
    int nnodes = min(NPB, N_NODES - node_base);

    float acc[16];
    #pragma unroll
    for (int r = 0; r < 16; ++r) acc[r] = 0.0f;
    if (tid < NPB) cnt_tot[tid] = 0;

    for (int cs = seg_beg; cs < seg_end; cs += CAP) {
        int m = min(CAP, seg_end - cs);
        __syncthreads();
        if (tid < NPB) hist[tid] = 0;
        __syncthreads();
        // load packed vals + local-node histogram
        for (int i = tid; i < m; i += blockDim.x) {
            unsigned v = packed[cs + i];
            buf[i] = v;
            atomicAdd(&hist[v >> 16], 1);
        }
        __syncthreads();
        // wave 0: exclusive scan of 64-bin hist
        if (tid < 64) {
            int v = hist[tid];
            int incl = v;
            #pragma unroll
            for (int ofs = 1; ofs < 64; ofs <<= 1) {
                int t = __shfl_up(incl, ofs);
                if (lane >= ofs) incl += t;
            }
            segoff[tid] = incl - v;
            cursor[tid] = incl - v;
            cnt_tot[tid] += v;
        }
        __syncthreads();
        // scatter srcs into node-sorted LDS order
        for (int i = tid; i < m; i += blockDim.x) {
            unsigned v = buf[i];
            int p = atomicAdd(&cursor[v >> 16], 1);
            srcs[p] = (unsigned short)(v & 0xFFFF);
        }
        __syncthreads();
        // aggregate: wave w owns nodes [w*16, w*16+16); lane = feature dim
        #pragma unroll
        for (int r = 0; r < 16; ++r) {
            int ln = wid * 16 + r;
            int st = segoff[ln];
            int len = hist[ln];
            int j = 0;
            for (; j + 3 < len; j += 4) {       // 4 independent gathers in flight
                int s0 = srcs[st + j + 0];
                int s1 = srcs[st + j + 1];
                int s2 = srcs[st + j + 2];
                int s3 = srcs[st + j + 3];
                float v0 = x[(size_t)s0 * DIM + lane];
                float v1 = x[(size_t)s1 * DIM + lane];
                float v2 = x[(size_t)s2 * DIM + lane];
                float v3 = x[(size_t)s3 * DIM + lane];
                acc[r] += v0 + v1 + v2 + v3;
            }
            for (; j < len; ++j)
                acc[r] += x[(size_t)srcs[st + j] * DIM + lane];
        }
    }
    __syncthreads();
    #pragma unroll
    for (int r = 0; r < 16; ++r) {
        int ln = wid * 16 + r;
        if (ln < nnodes) {
            int cnt = cnt_tot[ln];
            float inv = (cnt > 0) ? 1.0f / (float)cnt : 0.0f;
            out[(size_t)(node_base + ln) * DIM + lane] = acc[r] * inv;
        }
    }
}

extern "C" void kernel_launch(void* const* d_in, const int* in_sizes, int n_in,
                              void* d_out, int out_size, void* d_ws, size_t ws_size,
                              hipStream_t stream) {
    const float* x = (const float*)d_in[0];
    const int* edge_index = (const int*)d_in[1];  // [2, E] flat: row then col
    int E = in_sizes[1] / 2;
    const int* row = edge_index;
    const int* col = edge_index + E;
    float* out = (float*)d_out;

    int chunk = (E + NCHUNK - 1) / NCHUNK;

    // workspace layout (ints): bucket_total NB | bucket_base NB+1 | localH NCHUNK*NB | packed E
    int* bucket_total = (int*)d_ws;
    int* bucket_base  = bucket_total + NB;
    int* localH       = bucket_base + NB + 1;
    unsigned int* packed = (unsigned int*)(localH + NCHUNK * NB);

    hipMemsetAsync(bucket_total, 0, NB * sizeof(int), stream);

    bucket_hist_kernel<<<NCHUNK, 256, 0, stream>>>(col, localH, bucket_total, E, chunk);
    bucket_scan_kernel<<<1, 64, 0, stream>>>(bucket_total, bucket_base);
    chunk_offset_kernel<<<NB, 64, 0, stream>>>(localH, bucket_base);
    binning_kernel<<<NCHUNK, 256, 0, stream>>>(row, col, localH, packed, E, chunk);
    aggregate_bucket_kernel<<<NB, 256, 0, stream>>>(x, packed, bucket_base, out);
}

// Round 7
// 78.504 us; speedup vs baseline: 9.2579x; 1.1135x over previous
//
#include <hip/hip_runtime.h>

#define N_NODES 50000
#define DIM 64
#define NPB 64                                  // nodes per bucket (dst >> 6)
#define NB ((N_NODES + NPB - 1) / NPB)          // 782 buckets
#define NCHUNK 128                              // edge chunks (= binning blocks)
#define CAP 2048                                // aggregate per-iteration LDS capacity (edges)

typedef unsigned short ushort_t;

__device__ __forceinline__ ushort_t f32_to_bf16(float f) {
    unsigned u = __float_as_uint(f);
    // round-to-nearest-even on bit 16
    u += 0x7FFFu + ((u >> 16) & 1u);
    return (ushort_t)(u >> 16);
}

// ---- pass 0: convert x to bf16 (halves gather bytes; hot set ~fits L2) ----
__global__ void convert_bf16_kernel(const float* __restrict__ xf,
                                    ushort_t* __restrict__ xh, int n4) {
    int i = blockIdx.x * blockDim.x + threadIdx.x;
    int stride = gridDim.x * blockDim.x;
    for (; i < n4; i += stride) {
        float4 v = *reinterpret_cast<const float4*>(xf + (size_t)i * 4);
        ushort4 h;
        h.x = f32_to_bf16(v.x);
        h.y = f32_to_bf16(v.y);
        h.z = f32_to_bf16(v.z);
        h.w = f32_to_bf16(v.w);
        *reinterpret_cast<ushort4*>(xh + (size_t)i * 4) = h;
    }
}

// ---- B3a: per-chunk bucket histogram (LDS-privatized, int4 loads) ----
__global__ void bucket_hist_kernel(const int* __restrict__ col,
                                   int* __restrict__ localH,
                                   int* __restrict__ bucket_total,
                                   int E, int chunk) {
    __shared__ int h[NB];
    int c = blockIdx.x;
    int tid = threadIdx.x;
    for (int b = tid; b < NB; b += blockDim.x) h[b] = 0;
    __syncthreads();
    int beg = c * chunk, end = min(beg + chunk, E);
    int nfull = (end - beg) >> 2;
    for (int g = tid; g < nfull; g += blockDim.x) {
        int4 c4 = *reinterpret_cast<const int4*>(col + beg + g * 4);
        atomicAdd(&h[c4.x >> 6], 1);
        atomicAdd(&h[c4.y >> 6], 1);
        atomicAdd(&h[c4.z >> 6], 1);
        atomicAdd(&h[c4.w >> 6], 1);
    }
    for (int e = beg + nfull * 4 + tid; e < end; e += blockDim.x)
        atomicAdd(&h[col[e] >> 6], 1);
    __syncthreads();
    for (int b = tid; b < NB; b += blockDim.x) {
        int v = h[b];
        localH[(size_t)c * NB + b] = v;
        if (v) atomicAdd(&bucket_total[b], v);
    }
}

// ---- B3b0: exclusive scan of bucket totals -> bucket_base[0..NB] ----
__global__ void bucket_scan_kernel(const int* __restrict__ bucket_total,
                                   int* __restrict__ bucket_base) {
    int lane = threadIdx.x;                     // single wave
    int carry = 0;
    for (int b0 = 0; b0 < NB; b0 += 64) {
        int i = b0 + lane;
        int v = (i < NB) ? bucket_total[i] : 0;
        int incl = v;
        #pragma unroll
        for (int ofs = 1; ofs < 64; ofs <<= 1) {
            int t = __shfl_up(incl, ofs);
            if (lane >= ofs) incl += t;
        }
        if (i < NB) bucket_base[i] = carry + incl - v;
        carry += __shfl(incl, 63);
    }
    if (lane == 0) bucket_base[NB] = carry;
}

// ---- B3b: per-bucket prefix over chunks; IN-PLACE: localH becomes startpos ----
__global__ void chunk_offset_kernel(int* __restrict__ localH,
                                    const int* __restrict__ bucket_base) {
    int b = blockIdx.x;
    int lane = threadIdx.x;                     // single wave per bucket
    int running = bucket_base[b];
    for (int c0 = 0; c0 < NCHUNK; c0 += 64) {
        int c = c0 + lane;
        int v = (c < NCHUNK) ? localH[(size_t)c * NB + b] : 0;
        int incl = v;
        #pragma unroll
        for (int ofs = 1; ofs < 64; ofs <<= 1) {
            int t = __shfl_up(incl, ofs);
            if (lane >= ofs) incl += t;
        }
        if (c < NCHUNK) localH[(size_t)c * NB + b] = running + incl - v;
        running += __shfl(incl, 63);
    }
}

// ---- B3c: binning scatter — NO global atomics; block-exclusive regions ----
__global__ void binning_kernel(const int* __restrict__ row,
                               const int* __restrict__ col,
                               const int* __restrict__ startpos,
                               unsigned int* __restrict__ packed,
                               int E, int chunk) {
    __shared__ int cursor[NB];
    int c = blockIdx.x;
    int tid = threadIdx.x;
    for (int b = tid; b < NB; b += blockDim.x)
        cursor[b] = startpos[(size_t)c * NB + b];
    __syncthreads();
    int beg = c * chunk, end = min(beg + chunk, E);
    int nfull = (end - beg) >> 2;
    for (int g = tid; g < nfull; g += blockDim.x) {
        int e = beg + g * 4;
        int4 d4 = *reinterpret_cast<const int4*>(col + e);
        int4 s4 = *reinterpret_cast<const int4*>(row + e);
        int p0 = atomicAdd(&cursor[d4.x >> 6], 1);
        packed[p0] = (unsigned)s4.x | ((unsigned)(d4.x & 63) << 16);
        int p1 = atomicAdd(&cursor[d4.y >> 6], 1);
        packed[p1] = (unsigned)s4.y | ((unsigned)(d4.y & 63) << 16);
        int p2 = atomicAdd(&cursor[d4.z >> 6], 1);
        packed[p2] = (unsigned)s4.z | ((unsigned)(d4.z & 63) << 16);
        int p3 = atomicAdd(&cursor[d4.w >> 6], 1);
        packed[p3] = (unsigned)s4.w | ((unsigned)(d4.w & 63) << 16);
    }
    for (int e = beg + nfull * 4 + tid; e < end; e += blockDim.x) {
        int d = col[e];
        int p = atomicAdd(&cursor[d >> 6], 1);
        packed[p] = (unsigned)row[e] | ((unsigned)(d & 63) << 16);
    }
}

// ---- B4: fused per-bucket counting sort (LDS) + quarter-wave gather + mean ----
// 512 threads = 8 waves; wave w owns nodes [w*8, w*8+8).
// Gather: quarter q of a wave handles edge j+q -> 4 rows per load instruction.
template <bool BF16>
__global__ void aggregate_bucket_kernel(const float* __restrict__ xf,
                                        const ushort_t* __restrict__ xh,
                                        const unsigned int* __restrict__ packed,
                                        const int* __restrict__ bucket_base,
                                        float* __restrict__ out) {
    __shared__ unsigned int buf[CAP];
    __shared__ unsigned short srcs[CAP];
    __shared__ int hist[NPB];
    __shared__ int segoff[NPB];
    __shared__ int cursor[NPB];
    __shared__ int cnt_tot[NPB];

    int b = blockIdx.x;
    int tid = threadIdx.x;                      // 0..511
    int lane = tid & 63;
    int w = tid >> 6;                           // wave 0..7
    int q = lane >> 4;                          // quarter 0..3
    int rr = lane & 15;                         // dim group: covers dims rr*4..rr*4+3
    int seg_beg = bucket_base[b];
    int seg_end = bucket_base[b + 1];
    int node_base = b * NPB;
    int nnodes = min(NPB, N_NODES - node_base);

    float4 acc[8];
    #pragma unroll
    for (int r = 0; r < 8; ++r) acc[r] = make_float4(0.f, 0.f, 0.f, 0.f);
    if (tid < NPB) cnt_tot[tid] = 0;

    for (int cs = seg_beg; cs < seg_end; cs += CAP) {
        int m = min(CAP, seg_end - cs);
        __syncthreads();
        if (tid < NPB) hist[tid] = 0;
        __syncthreads();
        for (int i = tid; i < m; i += blockDim.x) {
            unsigned v = packed[cs + i];
            buf[i] = v;
            atomicAdd(&hist[v >> 16], 1);
        }
        __syncthreads();
        if (tid < 64) {                         // wave 0: scan 64 bins
            int v = hist[tid];
            int incl = v;
            #pragma unroll
            for (int ofs = 1; ofs < 64; ofs <<= 1) {
                int t = __shfl_up(incl, ofs);
                if (lane >= ofs) incl += t;
            }
            segoff[tid] = incl - v;
            cursor[tid] = incl - v;
            cnt_tot[tid] += v;
        }
        __syncthreads();
        for (int i = tid; i < m; i += blockDim.x) {
            unsigned v = buf[i];
            int p = atomicAdd(&cursor[v >> 16], 1);
            srcs[p] = (unsigned short)(v & 0xFFFF);
        }
        __syncthreads();
        #pragma unroll
        for (int r = 0; r < 8; ++r) {
            int ln = w * 8 + r;
            int st = segoff[ln];
            int len = hist[ln];
            int j = 0;
            for (; j + 8 <= len; j += 8) {      // 8 rows in flight per wave
                int s0 = srcs[st + j + q];
                int s1 = srcs[st + j + 4 + q];
                if (BF16) {
                    ushort4 h0 = *reinterpret_cast<const ushort4*>(xh + (size_t)s0 * DIM + rr * 4);
                    ushort4 h1 = *reinterpret_cast<const ushort4*>(xh + (size_t)s1 * DIM + rr * 4);
                    acc[r].x += __uint_as_float((unsigned)h0.x << 16) + __uint_as_float((unsigned)h1.x << 16);
                    acc[r].y += __uint_as_float((unsigned)h0.y << 16) + __uint_as_float((unsigned)h1.y << 16);
                    acc[r].z += __uint_as_float((unsigned)h0.z << 16) + __uint_as_float((unsigned)h1.z << 16);
                    acc[r].w += __uint_as_float((unsigned)h0.w << 16) + __uint_as_float((unsigned)h1.w << 16);
                } else {
                    float4 v0 = *reinterpret_cast<const float4*>(xf + (size_t)s0 * DIM + rr * 4);
                    float4 v1 = *reinterpret_cast<const float4*>(xf + (size_t)s1 * DIM + rr * 4);
                    acc[r].x += v0.x + v1.x;
                    acc[r].y += v0.y + v1.y;
                    acc[r].z += v0.z + v1.z;
                    acc[r].w += v0.w + v1.w;
                }
            }
            for (; j < len; j += 4) {
                if (j + q < len) {
                    int s = srcs[st + j + q];
                    if (BF16) {
                        ushort4 h0 = *reinterpret_cast<const ushort4*>(xh + (size_t)s * DIM + rr * 4);
                        acc[r].x += __uint_as_float((unsigned)h0.x << 16);
                        acc[r].y += __uint_as_float((unsigned)h0.y << 16);
                        acc[r].z += __uint_as_float((unsigned)h0.z << 16);
                        acc[r].w += __uint_as_float((unsigned)h0.w << 16);
                    } else {
                        float4 v0 = *reinterpret_cast<const float4*>(xf + (size_t)s * DIM + rr * 4);
                        acc[r].x += v0.x;
                        acc[r].y += v0.y;
                        acc[r].z += v0.z;
                        acc[r].w += v0.w;
                    }
                }
            }
        }
    }
    __syncthreads();
    // cross-quarter reduce (lanes rr, rr+16, rr+32, rr+48) + mean + store
    #pragma unroll
    for (int r = 0; r < 8; ++r) {
        int ln = w * 8 + r;
        float4 a = acc[r];
        a.x += __shfl_xor(a.x, 16); a.x += __shfl_xor(a.x, 32);
        a.y += __shfl_xor(a.y, 16); a.y += __shfl_xor(a.y, 32);
        a.z += __shfl_xor(a.z, 16); a.z += __shfl_xor(a.z, 32);
        a.w += __shfl_xor(a.w, 16); a.w += __shfl_xor(a.w, 32);
        if (q == 0 && ln < nnodes) {
            int cnt = cnt_tot[ln];
            float inv = (cnt > 0) ? 1.0f / (float)cnt : 0.0f;
            a.x *= inv; a.y *= inv; a.z *= inv; a.w *= inv;
            *reinterpret_cast<float4*>(out + (size_t)(node_base + ln) * DIM + rr * 4) = a;
        }
    }
}

extern "C" void kernel_launch(void* const* d_in, const int* in_sizes, int n_in,
                              void* d_out, int out_size, void* d_ws, size_t ws_size,
                              hipStream_t stream) {
    const float* x = (const float*)d_in[0];
    const int* edge_index = (const int*)d_in[1];  // [2, E] flat: row then col
    int E = in_sizes[1] / 2;
    const int* row = edge_index;
    const int* col = edge_index + E;
    float* out = (float*)d_out;

    int chunk = (((E + NCHUNK - 1) / NCHUNK) + 3) & ~3;   // multiple of 4

    // workspace layout: bucket_total NB | bucket_base NB+1 | localH NCHUNK*NB | packed E | xh N*DIM bf16
    int* bucket_total = (int*)d_ws;
    int* bucket_base  = bucket_total + NB;
    int* localH       = bucket_base + NB + 1;
    unsigned int* packed = (unsigned int*)(localH + (size_t)NCHUNK * NB);
    ushort_t* xh      = (ushort_t*)(packed + E);
    size_t need_bf16  = (size_t)((char*)(xh + (size_t)N_NODES * DIM) - (char*)d_ws);
    bool use_bf16 = (ws_size >= need_bf16);

    hipMemsetAsync(bucket_total, 0, NB * sizeof(int), stream);

    if (use_bf16)
        convert_bf16_kernel<<<1024, 256, 0, stream>>>(x, xh, N_NODES * DIM / 4);
    bucket_hist_kernel<<<NCHUNK, 1024, 0, stream>>>(col, localH, bucket_total, E, chunk);
    bucket_scan_kernel<<<1, 64, 0, stream>>>(bucket_total, bucket_base);
    chunk_offset_kernel<<<NB, 64, 0, stream>>>(localH, bucket_base);
    binning_kernel<<<NCHUNK, 1024, 0, stream>>>(row, col, localH, packed, E, chunk);
    if (use_bf16)
        aggregate_bucket_kernel<true><<<NB, 512, 0, stream>>>(x, xh, packed, bucket_base, out);
    else
        aggregate_bucket_kernel<false><<<NB, 512, 0, stream>>>(x, xh, packed, bucket_base, out);
}

// Round 8
// 77.809 us; speedup vs baseline: 9.3406x; 1.0089x over previous
//
#include <hip/hip_runtime.h>

#define N_NODES 50000
#define DIM 64
#define NPB 64                                  // nodes per bucket (dst >> 6)
#define NB ((N_NODES + NPB - 1) / NPB)          // 782 buckets
#define NCHUNK 256                              // edge chunks (= binning blocks)
#define CAP 2048                                // aggregate per-iteration LDS capacity (edges)

typedef unsigned short ushort_t;

__device__ __forceinline__ ushort_t f32_to_bf16(float f) {
    unsigned u = __float_as_uint(f);
    u += 0x7FFFu + ((u >> 16) & 1u);            // round-to-nearest-even
    return (ushort_t)(u >> 16);
}

// ---- pass 0: convert x to bf16 (halves gather bytes; hot set ~fits L2) ----
__global__ void convert_bf16_kernel(const float* __restrict__ xf,
                                    ushort_t* __restrict__ xh, int n4) {
    int i = blockIdx.x * blockDim.x + threadIdx.x;
    int stride = gridDim.x * blockDim.x;
    for (; i < n4; i += stride) {
        float4 v = *reinterpret_cast<const float4*>(xf + (size_t)i * 4);
        ushort4 h;
        h.x = f32_to_bf16(v.x);
        h.y = f32_to_bf16(v.y);
        h.z = f32_to_bf16(v.z);
        h.w = f32_to_bf16(v.w);
        *reinterpret_cast<ushort4*>(xh + (size_t)i * 4) = h;
    }
}

// ---- B3a: per-chunk bucket histogram (LDS-privatized, int4 loads) ----
// No global atomics, no bucket_total: totals derived later by column sum.
__global__ void bucket_hist_kernel(const int* __restrict__ col,
                                   int* __restrict__ localH,
                                   int E, int chunk) {
    __shared__ int h[NB];
    int c = blockIdx.x;
    int tid = threadIdx.x;
    for (int b = tid; b < NB; b += blockDim.x) h[b] = 0;
    __syncthreads();
    int beg = c * chunk, end = min(beg + chunk, E);
    int nfull = (end - beg) >> 2;
    for (int g = tid; g < nfull; g += blockDim.x) {
        int4 c4 = *reinterpret_cast<const int4*>(col + beg + g * 4);
        atomicAdd(&h[c4.x >> 6], 1);
        atomicAdd(&h[c4.y >> 6], 1);
        atomicAdd(&h[c4.z >> 6], 1);
        atomicAdd(&h[c4.w >> 6], 1);
    }
    for (int e = beg + nfull * 4 + tid; e < end; e += blockDim.x)
        atomicAdd(&h[col[e] >> 6], 1);
    __syncthreads();
    for (int b = tid; b < NB; b += blockDim.x)
        localH[(size_t)c * NB + b] = h[b];
}

// ---- B3b0: column-sum of localH + block-wide scan -> bucket_base[0..NB] ----
__global__ void colsum_scan_kernel(const int* __restrict__ localH,
                                   int* __restrict__ bucket_base) {
    __shared__ int sm[1024];
    int t = threadIdx.x;
    int sum = 0;
    if (t < NB) {
        #pragma unroll 4
        for (int c = 0; c < NCHUNK; ++c)
            sum += localH[(size_t)c * NB + t];  // consecutive t -> coalesced
    }
    sm[t] = sum;
    __syncthreads();
    for (int ofs = 1; ofs < 1024; ofs <<= 1) {  // Hillis-Steele inclusive scan
        int v = (t >= ofs) ? sm[t - ofs] : 0;
        __syncthreads();
        sm[t] += v;
        __syncthreads();
    }
    if (t < NB) bucket_base[t] = sm[t] - sum;   // exclusive
    if (t == NB - 1) bucket_base[NB] = sm[t];   // total
}

// ---- B3b: per-bucket prefix over chunks; IN-PLACE: localH becomes startpos ----
__global__ void chunk_offset_kernel(int* __restrict__ localH,
                                    const int* __restrict__ bucket_base) {
    int b = blockIdx.x;
    int lane = threadIdx.x;                     // single wave per bucket
    int running = bucket_base[b];
    for (int c0 = 0; c0 < NCHUNK; c0 += 64) {
        int c = c0 + lane;
        int v = (c < NCHUNK) ? localH[(size_t)c * NB + b] : 0;
        int incl = v;
        #pragma unroll
        for (int ofs = 1; ofs < 64; ofs <<= 1) {
            int t = __shfl_up(incl, ofs);
            if (lane >= ofs) incl += t;
        }
        if (c < NCHUNK) localH[(size_t)c * NB + b] = running + incl - v;
        running += __shfl(incl, 63);
    }
}

// ---- B3c: binning scatter — NO global atomics; block-exclusive regions ----
__global__ void binning_kernel(const int* __restrict__ row,
                               const int* __restrict__ col,
                               const int* __restrict__ startpos,
                               unsigned int* __restrict__ packed,
                               int E, int chunk) {
    __shared__ int cursor[NB];
    int c = blockIdx.x;
    int tid = threadIdx.x;
    for (int b = tid; b < NB; b += blockDim.x)
        cursor[b] = startpos[(size_t)c * NB + b];
    __syncthreads();
    int beg = c * chunk, end = min(beg + chunk, E);
    int nfull = (end - beg) >> 2;
    for (int g = tid; g < nfull; g += blockDim.x) {
        int e = beg + g * 4;
        int4 d4 = *reinterpret_cast<const int4*>(col + e);
        int4 s4 = *reinterpret_cast<const int4*>(row + e);
        int p0 = atomicAdd(&cursor[d4.x >> 6], 1);
        packed[p0] = (unsigned)s4.x | ((unsigned)(d4.x & 63) << 16);
        int p1 = atomicAdd(&cursor[d4.y >> 6], 1);
        packed[p1] = (unsigned)s4.y | ((unsigned)(d4.y & 63) << 16);
        int p2 = atomicAdd(&cursor[d4.z >> 6], 1);
        packed[p2] = (unsigned)s4.z | ((unsigned)(d4.z & 63) << 16);
        int p3 = atomicAdd(&cursor[d4.w >> 6], 1);
        packed[p3] = (unsigned)s4.w | ((unsigned)(d4.w & 63) << 16);
    }
    for (int e = beg + nfull * 4 + tid; e < end; e += blockDim.x) {
        int d = col[e];
        int p = atomicAdd(&cursor[d >> 6], 1);
        packed[p] = (unsigned)row[e] | ((unsigned)(d & 63) << 16);
    }
}

// ---- B4: fused per-bucket counting sort (LDS) + quarter-wave gather + mean ----
// 512 threads = 8 waves; wave w owns nodes [w*8, w*8+8).
// Gather: quarter q of a wave handles edge j+q -> 4 rows per load instruction.
template <bool BF16>
__global__ __launch_bounds__(512)
void aggregate_bucket_kernel(const float* __restrict__ xf,
                             const ushort_t* __restrict__ xh,
                             const unsigned int* __restrict__ packed,
                             const int* __restrict__ bucket_base,
                             float* __restrict__ out) {
    __shared__ unsigned int buf[CAP];
    __shared__ unsigned short srcs[CAP];
    __shared__ int hist[NPB];
    __shared__ int segoff[NPB];
    __shared__ int cursor[NPB];
    __shared__ int cnt_tot[NPB];

    int b = blockIdx.x;
    int tid = threadIdx.x;                      // 0..511
    int lane = tid & 63;
    int w = tid >> 6;                           // wave 0..7
    int q = lane >> 4;                          // quarter 0..3
    int rr = lane & 15;                         // dim group: covers dims rr*4..rr*4+3
    int seg_beg = bucket_base[b];
    int seg_end = bucket_base[b + 1];
    int node_base = b * NPB;
    int nnodes = min(NPB, N_NODES - node_base);

    float4 acc[8];
    #pragma unroll
    for (int r = 0; r < 8; ++r) acc[r] = make_float4(0.f, 0.f, 0.f, 0.f);
    if (tid < NPB) cnt_tot[tid] = 0;

    for (int cs = seg_beg; cs < seg_end; cs += CAP) {
        int m = min(CAP, seg_end - cs);
        __syncthreads();
        if (tid < NPB) hist[tid] = 0;
        __syncthreads();
        for (int i = tid; i < m; i += blockDim.x) {
            unsigned v = packed[cs + i];
            buf[i] = v;
            atomicAdd(&hist[v >> 16], 1);
        }
        __syncthreads();
        if (tid < 64) {                         // wave 0: scan 64 bins
            int v = hist[tid];
            int incl = v;
            #pragma unroll
            for (int ofs = 1; ofs < 64; ofs <<= 1) {
                int t = __shfl_up(incl, ofs);
                if (lane >= ofs) incl += t;
            }
            segoff[tid] = incl - v;
            cursor[tid] = incl - v;
            cnt_tot[tid] += v;
        }
        __syncthreads();
        for (int i = tid; i < m; i += blockDim.x) {
            unsigned v = buf[i];
            int p = atomicAdd(&cursor[v >> 16], 1);
            srcs[p] = (unsigned short)(v & 0xFFFF);
        }
        __syncthreads();
        #pragma unroll
        for (int r = 0; r < 8; ++r) {
            int ln = w * 8 + r;
            int st = segoff[ln];
            int len = hist[ln];
            int j = 0;
            for (; j + 8 <= len; j += 8) {      // 8 rows in flight per wave
                int s0 = srcs[st + j + q];
                int s1 = srcs[st + j + 4 + q];
                if (BF16) {
                    ushort4 h0 = *reinterpret_cast<const ushort4*>(xh + (size_t)s0 * DIM + rr * 4);
                    ushort4 h1 = *reinterpret_cast<const ushort4*>(xh + (size_t)s1 * DIM + rr * 4);
                    acc[r].x += __uint_as_float((unsigned)h0.x << 16) + __uint_as_float((unsigned)h1.x << 16);
                    acc[r].y += __uint_as_float((unsigned)h0.y << 16) + __uint_as_float((unsigned)h1.y << 16);
                    acc[r].z += __uint_as_float((unsigned)h0.z << 16) + __uint_as_float((unsigned)h1.z << 16);
                    acc[r].w += __uint_as_float((unsigned)h0.w << 16) + __uint_as_float((unsigned)h1.w << 16);
                } else {
                    float4 v0 = *reinterpret_cast<const float4*>(xf + (size_t)s0 * DIM + rr * 4);
                    float4 v1 = *reinterpret_cast<const float4*>(xf + (size_t)s1 * DIM + rr * 4);
                    acc[r].x += v0.x + v1.x;
                    acc[r].y += v0.y + v1.y;
                    acc[r].z += v0.z + v1.z;
                    acc[r].w += v0.w + v1.w;
                }
            }
            for (; j < len; j += 4) {
                if (j + q < len) {
                    int s = srcs[st + j + q];
                    if (BF16) {
                        ushort4 h0 = *reinterpret_cast<const ushort4*>(xh + (size_t)s * DIM + rr * 4);
                        acc[r].x += __uint_as_float((unsigned)h0.x << 16);
                        acc[r].y += __uint_as_float((unsigned)h0.y << 16);
                        acc[r].z += __uint_as_float((unsigned)h0.z << 16);
                        acc[r].w += __uint_as_float((unsigned)h0.w << 16);
                    } else {
                        float4 v0 = *reinterpret_cast<const float4*>(xf + (size_t)s * DIM + rr * 4);
                        acc[r].x += v0.x;
                        acc[r].y += v0.y;
                        acc[r].z += v0.z;
                        acc[r].w += v0.w;
                    }
                }
            }
        }
    }
    __syncthreads();
    // cross-quarter reduce (lanes rr, rr+16, rr+32, rr+48) + mean + store
    #pragma unroll
    for (int r = 0; r < 8; ++r) {
        int ln = w * 8 + r;
        float4 a = acc[r];
        a.x += __shfl_xor(a.x, 16); a.x += __shfl_xor(a.x, 32);
        a.y += __shfl_xor(a.y, 16); a.y += __shfl_xor(a.y, 32);
        a.z += __shfl_xor(a.z, 16); a.z += __shfl_xor(a.z, 32);
        a.w += __shfl_xor(a.w, 16); a.w += __shfl_xor(a.w, 32);
        if (q == 0 && ln < nnodes) {
            int cnt = cnt_tot[ln];
            float inv = (cnt > 0) ? 1.0f / (float)cnt : 0.0f;
            a.x *= inv; a.y *= inv; a.z *= inv; a.w *= inv;
            *reinterpret_cast<float4*>(out + (size_t)(node_base + ln) * DIM + rr * 4) = a;
        }
    }
}

extern "C" void kernel_launch(void* const* d_in, const int* in_sizes, int n_in,
                              void* d_out, int out_size, void* d_ws, size_t ws_size,
                              hipStream_t stream) {
    const float* x = (const float*)d_in[0];
    const int* edge_index = (const int*)d_in[1];  // [2, E] flat: row then col
    int E = in_sizes[1] / 2;
    const int* row = edge_index;
    const int* col = edge_index + E;
    float* out = (float*)d_out;

    int chunk = (((E + NCHUNK - 1) / NCHUNK) + 3) & ~3;   // multiple of 4

    // workspace layout: bucket_base NB+1 | localH NCHUNK*NB | packed E | xh N*DIM bf16
    int* bucket_base  = (int*)d_ws;
    int* localH       = bucket_base + NB + 1;
    unsigned int* packed = (unsigned int*)(localH + (size_t)NCHUNK * NB);
    ushort_t* xh      = (ushort_t*)(packed + E);
    size_t need_bf16  = (size_t)((char*)(xh + (size_t)N_NODES * DIM) - (char*)d_ws);
    bool use_bf16 = (ws_size >= need_bf16);

    if (use_bf16)
        convert_bf16_kernel<<<1024, 256, 0, stream>>>(x, xh, N_NODES * DIM / 4);
    bucket_hist_kernel<<<NCHUNK, 1024, 0, stream>>>(col, localH, E, chunk);
    colsum_scan_kernel<<<1, 1024, 0, stream>>>(localH, bucket_base);
    chunk_offset_kernel<<<NB, 64, 0, stream>>>(localH, bucket_base);
    binning_kernel<<<NCHUNK, 1024, 0, stream>>>(row, col, localH, packed, E, chunk);
    if (use_bf16)
        aggregate_bucket_kernel<true><<<NB, 512, 0, stream>>>(x, xh, packed, bucket_base, out);
    else
        aggregate_bucket_kernel<false><<<NB, 512, 0, stream>>>(x, xh, packed, bucket_base, out);
}

// Round 9
// 69.677 us; speedup vs baseline: 10.4307x; 1.1167x over previous
//
#include <hip/hip_runtime.h>

#define N_NODES 50000
#define DIM 64
#define NPB 64                                  // nodes per bucket (dst >> 6)
#define NB ((N_NODES + NPB - 1) / NPB)          // 782 buckets
#define NCHUNK 128                              // edge chunks (= binning blocks)
#define CAP 2048                                // aggregate per-iteration LDS capacity (edges)

typedef unsigned short ushort_t;

__device__ __forceinline__ ushort_t f32_to_bf16(float f) {
    unsigned u = __float_as_uint(f);
    u += 0x7FFFu + ((u >> 16) & 1u);            // round-to-nearest-even
    return (ushort_t)(u >> 16);
}

// ---- K1: fused convert(x->bf16) + per-chunk bucket histogram ----
__global__ void convert_hist_kernel(const float* __restrict__ xf,
                                    ushort_t* __restrict__ xh,
                                    const int* __restrict__ col,
                                    int* __restrict__ localH,
                                    int E, int chunk, int n4) {
    __shared__ int h[NB];
    int c = blockIdx.x;
    int tid = threadIdx.x;
    // convert: grid-stride over ushort4 groups (independent of hist)
    for (int i = c * blockDim.x + tid; i < n4; i += gridDim.x * blockDim.x) {
        float4 v = *reinterpret_cast<const float4*>(xf + (size_t)i * 4);
        ushort4 hh;
        hh.x = f32_to_bf16(v.x);
        hh.y = f32_to_bf16(v.y);
        hh.z = f32_to_bf16(v.z);
        hh.w = f32_to_bf16(v.w);
        *reinterpret_cast<ushort4*>(xh + (size_t)i * 4) = hh;
    }
    for (int b = tid; b < NB; b += blockDim.x) h[b] = 0;
    __syncthreads();
    int beg = c * chunk, end = min(beg + chunk, E);
    int nfull = (end - beg) >> 2;
    for (int g = tid; g < nfull; g += blockDim.x) {
        int4 c4 = *reinterpret_cast<const int4*>(col + beg + g * 4);
        atomicAdd(&h[c4.x >> 6], 1);
        atomicAdd(&h[c4.y >> 6], 1);
        atomicAdd(&h[c4.z >> 6], 1);
        atomicAdd(&h[c4.w >> 6], 1);
    }
    for (int e = beg + nfull * 4 + tid; e < end; e += blockDim.x)
        atomicAdd(&h[col[e] >> 6], 1);
    __syncthreads();
    for (int b = tid; b < NB; b += blockDim.x)
        localH[(size_t)c * NB + b] = h[b];
}

// ---- K2a: column-sum of localH + block-wide scan -> bucket_base[0..NB] ----
__global__ void colsum_scan_kernel(const int* __restrict__ localH,
                                   int* __restrict__ bucket_base) {
    __shared__ int sm[1024];
    int t = threadIdx.x;
    int sum = 0;
    if (t < NB) {
        #pragma unroll 4
        for (int c = 0; c < NCHUNK; ++c)
            sum += localH[(size_t)c * NB + t];  // consecutive t -> coalesced
    }
    sm[t] = sum;
    __syncthreads();
    for (int ofs = 1; ofs < 1024; ofs <<= 1) {  // Hillis-Steele inclusive scan
        int v = (t >= ofs) ? sm[t - ofs] : 0;
        __syncthreads();
        sm[t] += v;
        __syncthreads();
    }
    if (t < NB) bucket_base[t] = sm[t] - sum;   // exclusive
    if (t == NB - 1) bucket_base[NB] = sm[t];   // total
}

// ---- K2b: per-bucket prefix over chunks; IN-PLACE: localH becomes startpos ----
__global__ void chunk_offset_kernel(int* __restrict__ localH,
                                    const int* __restrict__ bucket_base) {
    int b = blockIdx.x;
    int lane = threadIdx.x;                     // single wave per bucket
    int running = bucket_base[b];
    for (int c0 = 0; c0 < NCHUNK; c0 += 64) {
        int c = c0 + lane;
        int v = (c < NCHUNK) ? localH[(size_t)c * NB + b] : 0;
        int incl = v;
        #pragma unroll
        for (int ofs = 1; ofs < 64; ofs <<= 1) {
            int t = __shfl_up(incl, ofs);
            if (lane >= ofs) incl += t;
        }
        if (c < NCHUNK) localH[(size_t)c * NB + b] = running + incl - v;
        running += __shfl(incl, 63);
    }
}

// ---- K3: binning scatter — NO global atomics; block-exclusive regions ----
__global__ void binning_kernel(const int* __restrict__ row,
                               const int* __restrict__ col,
                               const int* __restrict__ startpos,
                               unsigned int* __restrict__ packed,
                               int E, int chunk) {
    __shared__ int cursor[NB];
    int c = blockIdx.x;
    int tid = threadIdx.x;
    for (int b = tid; b < NB; b += blockDim.x)
        cursor[b] = startpos[(size_t)c * NB + b];
    __syncthreads();
    int beg = c * chunk, end = min(beg + chunk, E);
    int nfull = (end - beg) >> 2;
    for (int g = tid; g < nfull; g += blockDim.x) {
        int e = beg + g * 4;
        int4 d4 = *reinterpret_cast<const int4*>(col + e);
        int4 s4 = *reinterpret_cast<const int4*>(row + e);
        int p0 = atomicAdd(&cursor[d4.x >> 6], 1);
        packed[p0] = (unsigned)s4.x | ((unsigned)(d4.x & 63) << 16);
        int p1 = atomicAdd(&cursor[d4.y >> 6], 1);
        packed[p1] = (unsigned)s4.y | ((unsigned)(d4.y & 63) << 16);
        int p2 = atomicAdd(&cursor[d4.z >> 6], 1);
        packed[p2] = (unsigned)s4.z | ((unsigned)(d4.z & 63) << 16);
        int p3 = atomicAdd(&cursor[d4.w >> 6], 1);
        packed[p3] = (unsigned)s4.w | ((unsigned)(d4.w & 63) << 16);
    }
    for (int e = beg + nfull * 4 + tid; e < end; e += blockDim.x) {
        int d = col[e];
        int p = atomicAdd(&cursor[d >> 6], 1);
        packed[p] = (unsigned)row[e] | ((unsigned)(d & 63) << 16);
    }
}

// ---- K4: fused per-bucket counting sort (LDS) + quarter-wave gather + mean ----
// 512 threads = 8 waves; wave w owns nodes [w*8, w*8+8).
// Gather: quarter q handles edges j+q, j+4+q, j+8+q, j+12+q -> 16 rows in flight.
template <bool BF16>
__global__ __launch_bounds__(512)
void aggregate_bucket_kernel(const float* __restrict__ xf,
                             const ushort_t* __restrict__ xh,
                             const unsigned int* __restrict__ packed,
                             const int* __restrict__ bucket_base,
                             float* __restrict__ out) {
    __shared__ unsigned int buf[CAP];
    __shared__ unsigned short srcs[CAP];
    __shared__ int hist[NPB];
    __shared__ int segoff[NPB];
    __shared__ int cursor[NPB];
    __shared__ int cnt_tot[NPB];

    int b = blockIdx.x;
    int tid = threadIdx.x;                      // 0..511
    int lane = tid & 63;
    int w = tid >> 6;                           // wave 0..7
    int q = lane >> 4;                          // quarter 0..3
    int rr = lane & 15;                         // dim group: covers dims rr*4..rr*4+3
    int seg_beg = bucket_base[b];
    int seg_end = bucket_base[b + 1];
    int node_base = b * NPB;
    int nnodes = min(NPB, N_NODES - node_base);

    float4 acc[8];
    #pragma unroll
    for (int r = 0; r < 8; ++r) acc[r] = make_float4(0.f, 0.f, 0.f, 0.f);
    if (tid < NPB) cnt_tot[tid] = 0;

    for (int cs = seg_beg; cs < seg_end; cs += CAP) {
        int m = min(CAP, seg_end - cs);
        __syncthreads();
        if (tid < NPB) hist[tid] = 0;
        __syncthreads();
        for (int i = tid; i < m; i += blockDim.x) {
            unsigned v = packed[cs + i];
            buf[i] = v;
            atomicAdd(&hist[v >> 16], 1);
        }
        __syncthreads();
        if (tid < 64) {                         // wave 0: scan 64 bins
            int v = hist[tid];
            int incl = v;
            #pragma unroll
            for (int ofs = 1; ofs < 64; ofs <<= 1) {
                int t = __shfl_up(incl, ofs);
                if (lane >= ofs) incl += t;
            }
            segoff[tid] = incl - v;
            cursor[tid] = incl - v;
            cnt_tot[tid] += v;
        }
        __syncthreads();
        for (int i = tid; i < m; i += blockDim.x) {
            unsigned v = buf[i];
            int p = atomicAdd(&cursor[v >> 16], 1);
            srcs[p] = (unsigned short)(v & 0xFFFF);
        }
        __syncthreads();
        #pragma unroll
        for (int r = 0; r < 8; ++r) {
            int ln = w * 8 + r;
            int st = segoff[ln];
            int len = hist[ln];
            int j = 0;
            for (; j + 16 <= len; j += 16) {    // 16 rows in flight per wave
                int s0 = srcs[st + j + q];
                int s1 = srcs[st + j + 4 + q];
                int s2 = srcs[st + j + 8 + q];
                int s3 = srcs[st + j + 12 + q];
                if (BF16) {
                    ushort4 h0 = *reinterpret_cast<const ushort4*>(xh + (size_t)s0 * DIM + rr * 4);
                    ushort4 h1 = *reinterpret_cast<const ushort4*>(xh + (size_t)s1 * DIM + rr * 4);
                    ushort4 h2 = *reinterpret_cast<const ushort4*>(xh + (size_t)s2 * DIM + rr * 4);
                    ushort4 h3 = *reinterpret_cast<const ushort4*>(xh + (size_t)s3 * DIM + rr * 4);
                    acc[r].x += __uint_as_float((unsigned)h0.x << 16) + __uint_as_float((unsigned)h1.x << 16)
                              + __uint_as_float((unsigned)h2.x << 16) + __uint_as_float((unsigned)h3.x << 16);
                    acc[r].y += __uint_as_float((unsigned)h0.y << 16) + __uint_as_float((unsigned)h1.y << 16)
                              + __uint_as_float((unsigned)h2.y << 16) + __uint_as_float((unsigned)h3.y << 16);
                    acc[r].z += __uint_as_float((unsigned)h0.z << 16) + __uint_as_float((unsigned)h1.z << 16)
                              + __uint_as_float((unsigned)h2.z << 16) + __uint_as_float((unsigned)h3.z << 16);
                    acc[r].w += __uint_as_float((unsigned)h0.w << 16) + __uint_as_float((unsigned)h1.w << 16)
                              + __uint_as_float((unsigned)h2.w << 16) + __uint_as_float((unsigned)h3.w << 16);
                } else {
                    float4 v0 = *reinterpret_cast<const float4*>(xf + (size_t)s0 * DIM + rr * 4);
                    float4 v1 = *reinterpret_cast<const float4*>(xf + (size_t)s1 * DIM + rr * 4);
                    float4 v2 = *reinterpret_cast<const float4*>(xf + (size_t)s2 * DIM + rr * 4);
                    float4 v3 = *reinterpret_cast<const float4*>(xf + (size_t)s3 * DIM + rr * 4);
                    acc[r].x += v0.x + v1.x + v2.x + v3.x;
                    acc[r].y += v0.y + v1.y + v2.y + v3.y;
                    acc[r].z += v0.z + v1.z + v2.z + v3.z;
                    acc[r].w += v0.w + v1.w + v2.w + v3.w;
                }
            }
            for (; j < len; j += 4) {
                if (j + q < len) {
                    int s = srcs[st + j + q];
                    if (BF16) {
                        ushort4 h0 = *reinterpret_cast<const ushort4*>(xh + (size_t)s * DIM + rr * 4);
                        acc[r].x += __uint_as_float((unsigned)h0.x << 16);
                        acc[r].y += __uint_as_float((unsigned)h0.y << 16);
                        acc[r].z += __uint_as_float((unsigned)h0.z << 16);
                        acc[r].w += __uint_as_float((unsigned)h0.w << 16);
                    } else {
                        float4 v0 = *reinterpret_cast<const float4*>(xf + (size_t)s * DIM + rr * 4);
                        acc[r].x += v0.x;
                        acc[r].y += v0.y;
                        acc[r].z += v0.z;
                        acc[r].w += v0.w;
                    }
                }
            }
        }
    }
    __syncthreads();
    // cross-quarter reduce (lanes rr, rr+16, rr+32, rr+48) + mean + store
    #pragma unroll
    for (int r = 0; r < 8; ++r) {
        int ln = w * 8 + r;
        float4 a = acc[r];
        a.x += __shfl_xor(a.x, 16); a.x += __shfl_xor(a.x, 32);
        a.y += __shfl_xor(a.y, 16); a.y += __shfl_xor(a.y, 32);
        a.z += __shfl_xor(a.z, 16); a.z += __shfl_xor(a.z, 32);
        a.w += __shfl_xor(a.w, 16); a.w += __shfl_xor(a.w, 32);
        if (q == 0 && ln < nnodes) {
            int cnt = cnt_tot[ln];
            float inv = (cnt > 0) ? 1.0f / (float)cnt : 0.0f;
            a.x *= inv; a.y *= inv; a.z *= inv; a.w *= inv;
            *reinterpret_cast<float4*>(out + (size_t)(node_base + ln) * DIM + rr * 4) = a;
        }
    }
}

extern "C" void kernel_launch(void* const* d_in, const int* in_sizes, int n_in,
                              void* d_out, int out_size, void* d_ws, size_t ws_size,
                              hipStream_t stream) {
    const float* x = (const float*)d_in[0];
    const int* edge_index = (const int*)d_in[1];  // [2, E] flat: row then col
    int E = in_sizes[1] / 2;
    const int* row = edge_index;
    const int* col = edge_index + E;
    float* out = (float*)d_out;

    int chunk = (((E + NCHUNK - 1) / NCHUNK) + 3) & ~3;   // multiple of 4

    // workspace layout: bucket_base 784 | localH NCHUNK*NB | packed E | xh N*DIM bf16
    int* bucket_base  = (int*)d_ws;               // NB+1 used, padded to 784 (16B align)
    int* localH       = bucket_base + 784;
    unsigned int* packed = (unsigned int*)(localH + (size_t)NCHUNK * NB);
    ushort_t* xh      = (ushort_t*)(packed + E);
    size_t need_bf16  = (size_t)((char*)(xh + (size_t)N_NODES * DIM) - (char*)d_ws);
    bool use_bf16 = (ws_size >= need_bf16);

    if (use_bf16)
        convert_hist_kernel<<<NCHUNK, 1024, 0, stream>>>(x, xh, col, localH, E, chunk,
                                                         N_NODES * DIM / 4);
    else
        convert_hist_kernel<<<NCHUNK, 1024, 0, stream>>>(x, (ushort_t*)packed /*unused*/,
                                                         col, localH, E, chunk, 0);
    colsum_scan_kernel<<<1, 1024, 0, stream>>>(localH, bucket_base);
    chunk_offset_kernel<<<NB, 64, 0, stream>>>(localH, bucket_base);
    binning_kernel<<<NCHUNK, 1024, 0, stream>>>(row, col, localH, packed, E, chunk);
    if (use_bf16)
        aggregate_bucket_kernel<true><<<NB, 512, 0, stream>>>(x, xh, packed, bucket_base, out);
    else
        aggregate_bucket_kernel<false><<<NB, 512, 0, stream>>>(x, xh, packed, bucket_base, out);
}